// Round 5
// baseline (1176.961 us; speedup 1.0000x reference)
//
#include <hip/hip_runtime.h>
#include <hip/hip_bf16.h>

typedef __bf16 bf16_t;
typedef __bf16 bf16x8 __attribute__((ext_vector_type(8)));
typedef __bf16 bf16x4 __attribute__((ext_vector_type(4)));
typedef float  f32x4  __attribute__((ext_vector_type(4)));
typedef unsigned long long u64;

#define HID 512
#define BATCH 256
#define TIN 168
#define TOUT 48
#define FEAT 128
#define NSTEPS (TIN + TOUT)   // 216
#define NGRP 8                // batch groups (blocks of a group: bid ≡ g mod 8)
#define NJT 32                // blocks per group (j-tiles of 16)
#define GRPB 32               // batch rows per group

__device__ __forceinline__ float sigmoidf_(float x) {
    x = fminf(fmaxf(x, -30.f), 30.f);
    return 1.f / (1.f + __expf(-x));
}
__device__ __forceinline__ float tanhf_(float x) {
    x = fminf(fmaxf(x, -15.f), 15.f);
    float e = __expf(2.f * x);
    return (e - 1.f) / (e + 1.f);
}

// Scope-parameterized coherent loads/stores. SCOPE_AGENT -> sc0 (XCD L2
// coherence point, valid only if all communicating blocks share an XCD —
// verified at runtime). SCOPE_SYSTEM -> sc0 sc1 (IC coherence point, always
// valid). RELAXED => no cache-maintenance (no buffer_inv/wbl2).
template <int SCOPE>
__device__ __forceinline__ bf16x8 ld_h8(const bf16_t* p) {
    union { u64 q[2]; bf16x8 v; } u;
    u.q[0] = __hip_atomic_load((const u64*)p,     __ATOMIC_RELAXED, SCOPE);
    u.q[1] = __hip_atomic_load((const u64*)p + 1, __ATOMIC_RELAXED, SCOPE);
    return u.v;
}
template <int SCOPE>
__device__ __forceinline__ void st_h16(bf16_t* p, bf16x8 v) {
    union { bf16x8 v; u64 q[2]; } u;
    u.v = v;
    __hip_atomic_store((u64*)p,     u.q[0], __ATOMIC_RELAXED, SCOPE);
    __hip_atomic_store((u64*)p + 1, u.q[1], __ATOMIC_RELAXED, SCOPE);
}

// ---------------------------------------------------------------------------
// Cast x (B,T,F) fp32 -> Xbf (T,B,F) bf16
__global__ __launch_bounds__(256)
void cast_x_kernel(const float* __restrict__ x, bf16_t* __restrict__ Xbf) {
    int q = blockIdx.x * 256 + threadIdx.x;
    if (q >= BATCH * TIN * (FEAT / 4)) return;
    int f4  = q & 31;
    int rem = q >> 5;
    int t = rem % TIN;
    int b = rem / TIN;
    float4 v = *(const float4*)&x[((size_t)b * TIN + t) * FEAT + f4 * 4];
    bf16x4 o = { (bf16_t)v.x, (bf16_t)v.y, (bf16_t)v.z, (bf16_t)v.w };
    *(bf16x4*)&Xbf[((size_t)t * BATCH + b) * FEAT + f4 * 4] = o;
}

// Build Wcat (2048 x 640) bf16 = [Wih | Whh]
__global__ __launch_bounds__(256)
void cast_wcat_kernel(const float* __restrict__ Wih, const float* __restrict__ Whh,
                      bf16_t* __restrict__ Wcat) {
    int q = blockIdx.x * 256 + threadIdx.x;
    int k4 = q % 160;
    int r  = q / 160;
    if (r >= 2048) return;
    int k = k4 * 4;
    float4 v;
    if (k < FEAT) v = *(const float4*)&Wih[(size_t)r * FEAT + k];
    else          v = *(const float4*)&Whh[(size_t)r * HID + (k - FEAT)];
    bf16x4 o = { (bf16_t)v.x, (bf16_t)v.y, (bf16_t)v.z, (bf16_t)v.w };
    *(bf16x4*)&Wcat[(size_t)r * 640 + k] = o;
}

// Cast W_lin (128 x 512) fp32 -> bf16
__global__ __launch_bounds__(256)
void cast_wlin_kernel(const float* __restrict__ W, bf16_t* __restrict__ Wb) {
    int q = blockIdx.x * 256 + threadIdx.x;
    if (q >= FEAT * HID / 4) return;
    float4 v = *(const float4*)&W[q * 4];
    bf16x4 o = { (bf16_t)v.x, (bf16_t)v.y, (bf16_t)v.z, (bf16_t)v.w };
    *(bf16x4*)&Wb[q * 4] = o;
}

// Wcomb (2048 x 512) = dec_Wih (2048x128) @ W_lin (128x512) + dec_Whh, bf16 out
__global__ __launch_bounds__(256)
void build_wcomb_kernel(const float* __restrict__ dWih, const float* __restrict__ dWhh,
                        const float* __restrict__ Wlin, bf16_t* __restrict__ Wcomb) {
    __shared__ float As[64][128];
    __shared__ float Bs[128][64];
    int r0 = blockIdx.x * 64, c0 = blockIdx.y * 64;
    int tid = threadIdx.x;
    for (int i = tid; i < 64 * 32; i += 256) {
        int rr = i >> 5, cc = (i & 31) << 2;
        *(float4*)&As[rr][cc] = *(const float4*)&dWih[(size_t)(r0 + rr) * 128 + cc];
    }
    for (int i = tid; i < 128 * 16; i += 256) {
        int kk = i >> 4, cc = (i & 15) << 2;
        *(float4*)&Bs[kk][cc] = *(const float4*)&Wlin[(size_t)kk * HID + c0 + cc];
    }
    __syncthreads();
    int tx = tid & 15, ty = tid >> 4;
    float acc[4][4] = {};
    for (int k = 0; k < 128; ++k) {
        float a[4], b[4];
        #pragma unroll
        for (int i = 0; i < 4; ++i) a[i] = As[ty * 4 + i][k];
        #pragma unroll
        for (int j = 0; j < 4; ++j) b[j] = Bs[k][tx * 4 + j];
        #pragma unroll
        for (int i = 0; i < 4; ++i)
            #pragma unroll
            for (int j = 0; j < 4; ++j) acc[i][j] += a[i] * b[j];
    }
    for (int i = 0; i < 4; ++i) {
        int r = r0 + ty * 4 + i;
        for (int j = 0; j < 4; ++j) {
            int cc = c0 + tx * 4 + j;
            Wcomb[(size_t)r * HID + cc] = (bf16_t)(acc[i][j] + dWhh[(size_t)r * HID + cc]);
        }
    }
}

// ---------------------------------------------------------------------------
// Persistent seq2seq LSTM. 256 blocks x 256 threads.
// Block -> (group g = bid&7, j-tile jt = bid>>3). Group owns 32 batch rows;
// block owns 16 hidden cols. 4 waves: bh = batch half, gp = K half.
// Weights pinned in V/AGPRs; c register-resident. h exchange + epoch flags go
// through the runtime-selected coherence point (XCD L2 if group colocated,
// else IC).

template <int SCOPE>
__device__ __forceinline__ void cell_finish(
    f32x4 (&acc)[4], float (&cacc)[4], float (*Ex)[GRPB][18], bf16_t (*Hs)[16],
    int gp, int bh, int l4, int l15, int lane, int gbase, int j0,
    bf16_t* __restrict__ hnext)
{
    if (gp == 1) {
        #pragma unroll
        for (int q = 0; q < 4; ++q)
            #pragma unroll
            for (int r = 0; r < 4; ++r)
                Ex[q][bh * 16 + l4 * 4 + r][l15] = acc[q][r];
    }
    __syncthreads();
    if (gp == 0) {
        #pragma unroll
        for (int q = 0; q < 4; ++q)
            #pragma unroll
            for (int r = 0; r < 4; ++r)
                acc[q][r] += Ex[q][bh * 16 + l4 * 4 + r][l15];
        #pragma unroll
        for (int r = 0; r < 4; ++r) {
            float cn = sigmoidf_(acc[1][r]) * cacc[r] + sigmoidf_(acc[0][r]) * tanhf_(acc[2][r]);
            cacc[r] = cn;
            float hv = sigmoidf_(acc[3][r]) * tanhf_(cn);
            Hs[bh * 16 + l4 * 4 + r][l15] = (bf16_t)hv;   // stage in LDS
        }
        // wave-local readback -> wide 16B coherent stores (64 per block, not 512x2B)
        if (lane < 32) {
            int row  = bh * 16 + (lane >> 1);
            int half = lane & 1;
            bf16x8 v = *(const bf16x8*)&Hs[row][half * 8];
            st_h16<SCOPE>(hnext + (size_t)(gbase + row) * HID + j0 + half * 8, v);
        }
        asm volatile("s_waitcnt vmcnt(0)" ::: "memory");   // drain before flag
    }
    __syncthreads();
}

// wait until all 32 blocks of group g have flag >= epoch
template <int SCOPE>
__device__ __forceinline__ void group_wait(const unsigned int* flags, int g, int tid,
                                           unsigned int epoch) {
    if (tid < NJT) {
        while (__hip_atomic_load(&flags[g * NJT + tid], __ATOMIC_RELAXED, SCOPE) < epoch)
            __builtin_amdgcn_s_sleep(1);
    }
    __syncthreads();
}

template <int SCOPE>
__device__ __forceinline__ void group_arrive(unsigned int* flags, int g, int jt, int tid,
                                             unsigned int epoch) {
    if (tid == 0)
        __hip_atomic_store(&flags[g * NJT + jt], epoch, __ATOMIC_RELAXED, SCOPE);
}

template <int SCOPE>
__device__ void run_steps(const bf16_t* __restrict__ Xbf,
                          const bf16_t* __restrict__ Wenc, const float* __restrict__ enc_b,
                          const bf16_t* __restrict__ Wdec1, const bf16_t* __restrict__ Wcomb,
                          const float* __restrict__ dec_b,
                          bf16_t* __restrict__ hbufA, bf16_t* __restrict__ hbufB,
                          bf16_t* __restrict__ Hdec, unsigned int* __restrict__ flags,
                          float (*Ex)[GRPB][18], bf16_t (*Hs)[16],
                          int g, int jt, int tid)
{
    const int j0  = jt * 16;
    const int wave = tid >> 6, lane = tid & 63;
    const int l15 = lane & 15, l4 = lane >> 4;
    const int bh = wave & 1, gp = wave >> 1;
    const int gbase = g * GRPB;
    const int b0 = gbase + bh * 16;
    const int arow = b0 + l15;   // A-operand (batch) row this lane loads
    const int jcol = j0 + l15;   // output hidden column

    float biasE[4], biasD[4];
    #pragma unroll
    for (int q = 0; q < 4; ++q) {
        biasE[q] = enc_b[q * HID + jcol];
        biasD[q] = dec_b[q * HID + jcol];
    }
    float cacc[4] = {0.f, 0.f, 0.f, 0.f};

    bf16x8 Breg[40];
    const int kc0 = gp * 320;    // K-half base for K=640 phases

    // ---- encoder weight fragments (K=640), pinned
    #pragma unroll
    for (int q = 0; q < 4; ++q)
        #pragma unroll
        for (int i = 0; i < 10; ++i)
            Breg[q * 10 + i] = *(const bf16x8*)(
                Wenc + (size_t)(q * HID + jcol) * 640 + kc0 + i * 32 + l4 * 8);
    #pragma unroll
    for (int n = 0; n < 40; ++n) asm volatile("" : "+v"(Breg[n]));

    // ================= encoder: t = 0..167 =================
    for (int t = 0; t < TIN; ++t) {
        if (t > 0) group_wait<SCOPE>(flags, g, tid, (unsigned)t);
        const bf16_t* hb = (t & 1) ? hbufB : hbufA;
        bf16_t* hn       = (t & 1) ? hbufA : hbufB;
        f32x4 acc[4];
        #pragma unroll
        for (int q = 0; q < 4; ++q) {
            float bv = (gp == 0) ? biasE[q] : 0.f;
            acc[q] = (f32x4){bv, bv, bv, bv};
        }
        const bf16_t* xb  = Xbf + ((size_t)t * BATCH + arow) * FEAT + l4 * 8;
        const bf16_t* hbp = hb + (size_t)arow * HID + l4 * 8;
        #pragma unroll
        for (int i = 0; i < 10; ++i) {
            int kc = kc0 + i * 32;
            bf16x8 a;
            if (kc < FEAT) a = *(const bf16x8*)(xb + kc);
            else           a = ld_h8<SCOPE>(hbp + (kc - FEAT));
            #pragma unroll
            for (int q = 0; q < 4; ++q)
                acc[q] = __builtin_amdgcn_mfma_f32_16x16x32_bf16(a, Breg[q * 10 + i], acc[q], 0, 0, 0);
        }
        cell_finish<SCOPE>(acc, cacc, Ex, Hs, gp, bh, l4, l15, lane, gbase, j0, hn);
        group_arrive<SCOPE>(flags, g, jt, tid, (unsigned)(t + 1));
    }

    // ---- decoder step 0 weights (Wdec1, K=640)
    #pragma unroll
    for (int q = 0; q < 4; ++q)
        #pragma unroll
        for (int i = 0; i < 10; ++i)
            Breg[q * 10 + i] = *(const bf16x8*)(
                Wdec1 + (size_t)(q * HID + jcol) * 640 + kc0 + i * 32 + l4 * 8);
    #pragma unroll
    for (int n = 0; n < 40; ++n) asm volatile("" : "+v"(Breg[n]));

    // ================= decoder step 0: t = 168 =================
    {
        const int t = TIN;
        group_wait<SCOPE>(flags, g, tid, (unsigned)t);
        // h_168 lives in hbufA (written at t=167, odd)
        f32x4 acc[4];
        #pragma unroll
        for (int q = 0; q < 4; ++q) {
            float bv = (gp == 0) ? biasD[q] : 0.f;
            acc[q] = (f32x4){bv, bv, bv, bv};
        }
        const bf16_t* xb  = Xbf + ((size_t)(TIN - 1) * BATCH + arow) * FEAT + l4 * 8;
        const bf16_t* hbp = hbufA + (size_t)arow * HID + l4 * 8;
        #pragma unroll
        for (int i = 0; i < 10; ++i) {
            int kc = kc0 + i * 32;
            bf16x8 a;
            if (kc < FEAT) a = *(const bf16x8*)(xb + kc);
            else           a = ld_h8<SCOPE>(hbp + (kc - FEAT));
            #pragma unroll
            for (int q = 0; q < 4; ++q)
                acc[q] = __builtin_amdgcn_mfma_f32_16x16x32_bf16(a, Breg[q * 10 + i], acc[q], 0, 0, 0);
        }
        cell_finish<SCOPE>(acc, cacc, Ex, Hs, gp, bh, l4, l15, lane, gbase, j0, Hdec);
        group_arrive<SCOPE>(flags, g, jt, tid, (unsigned)(t + 1));
    }

    // ---- folded decoder weights (Wcomb, K=512)
    const int kd0 = gp * 256;
    #pragma unroll
    for (int q = 0; q < 4; ++q)
        #pragma unroll
        for (int i = 0; i < 8; ++i)
            Breg[q * 8 + i] = *(const bf16x8*)(
                Wcomb + (size_t)(q * HID + jcol) * HID + kd0 + i * 32 + l4 * 8);
    #pragma unroll
    for (int n = 0; n < 32; ++n) asm volatile("" : "+v"(Breg[n]));

    // ================= decoder: t = 169..215 =================
    for (int t = TIN + 1; t < NSTEPS; ++t) {
        group_wait<SCOPE>(flags, g, tid, (unsigned)t);
        const bf16_t* hprev = Hdec + (size_t)(t - 1 - TIN) * BATCH * HID
                                   + (size_t)arow * HID + l4 * 8;
        f32x4 acc[4];
        #pragma unroll
        for (int q = 0; q < 4; ++q) {
            float bv = (gp == 0) ? biasD[q] : 0.f;
            acc[q] = (f32x4){bv, bv, bv, bv};
        }
        #pragma unroll
        for (int i = 0; i < 8; ++i) {
            bf16x8 a = ld_h8<SCOPE>(hprev + kd0 + i * 32);
            #pragma unroll
            for (int q = 0; q < 4; ++q)
                acc[q] = __builtin_amdgcn_mfma_f32_16x16x32_bf16(a, Breg[q * 8 + i], acc[q], 0, 0, 0);
        }
        cell_finish<SCOPE>(acc, cacc, Ex, Hs, gp, bh, l4, l15, lane, gbase, j0,
                           Hdec + (size_t)(t - TIN) * BATCH * HID);
        group_arrive<SCOPE>(flags, g, jt, tid, (unsigned)(t + 1));
    }
}

__global__ __launch_bounds__(256, 1)
void lstm_persist(const bf16_t* __restrict__ Xbf,
                  const bf16_t* __restrict__ Wenc, const float* __restrict__ enc_b,
                  const bf16_t* __restrict__ Wdec1, const bf16_t* __restrict__ Wcomb,
                  const float* __restrict__ dec_b,
                  bf16_t* __restrict__ hbufA, bf16_t* __restrict__ hbufB,
                  bf16_t* __restrict__ Hdec, unsigned int* __restrict__ flags,
                  unsigned int* __restrict__ xccbuf)
{
    __shared__ float  Ex[4][GRPB][18];
    __shared__ bf16_t Hs[GRPB][16];
    __shared__ int    fastflag;
    const int bid = blockIdx.x;
    const int g   = bid & (NGRP - 1);
    const int jt  = bid >> 3;
    const int tid = threadIdx.x;
    const int lane = tid & 63;

    // ---- runtime XCD-colocation discovery for this group ----
    unsigned int xcc;
    asm volatile("s_getreg_b32 %0, hwreg(HW_REG_XCC_ID)" : "=s"(xcc));
    if (tid == 0)
        __hip_atomic_store(&xccbuf[bid], xcc + 1u, __ATOMIC_RELAXED,
                           __HIP_MEMORY_SCOPE_SYSTEM);
    if (tid < 64) {           // wave 0
        unsigned int v = 0;
        if (lane < NJT) {
            do {
                v = __hip_atomic_load(&xccbuf[g + NGRP * lane], __ATOMIC_RELAXED,
                                      __HIP_MEMORY_SCOPE_SYSTEM);
                if (v == 0) __builtin_amdgcn_s_sleep(1);
            } while (v == 0);
        }
        bool ok = (lane >= NJT) || (v == xcc + 1u);
        unsigned long long m = __ballot(ok);
        if (lane == 0) fastflag = (m == ~0ull) ? 1 : 0;
    }
    __syncthreads();
    const bool fast = (fastflag != 0);

    if (fast)
        run_steps<__HIP_MEMORY_SCOPE_AGENT>(Xbf, Wenc, enc_b, Wdec1, Wcomb, dec_b,
                                            hbufA, hbufB, Hdec, flags, Ex, Hs, g, jt, tid);
    else
        run_steps<__HIP_MEMORY_SCOPE_SYSTEM>(Xbf, Wenc, enc_b, Wdec1, Wcomb, dec_b,
                                             hbufA, hbufB, Hdec, flags, Ex, Hs, g, jt, tid);
}

// ---------------------------------------------------------------------------
// Final projection: out[b,t,f] = sum_j Hdec[t][b][j] * Wlin[f][j]
__global__ __launch_bounds__(128)
void final_proj_kernel(const bf16_t* __restrict__ Hdec, const bf16_t* __restrict__ Wlin,
                       float* __restrict__ out) {
    int tid = threadIdx.x;
    int wv = tid >> 6, lane = tid & 63;
    int l15 = lane & 15, l4 = lane >> 4;
    int row0 = blockIdx.x * 32 + wv * 16;
    const bf16_t* arow = Hdec + (size_t)(row0 + l15) * HID;
    f32x4 acc[8];
    #pragma unroll
    for (int n = 0; n < 8; ++n) acc[n] = (f32x4){0.f, 0.f, 0.f, 0.f};
    #pragma unroll 4
    for (int kc = 0; kc < HID; kc += 32) {
        bf16x8 af = *(const bf16x8*)(arow + kc + l4 * 8);
        #pragma unroll
        for (int n = 0; n < 8; ++n) {
            bf16x8 bfr = *(const bf16x8*)(Wlin + (size_t)(n * 16 + l15) * HID + kc + l4 * 8);
            acc[n] = __builtin_amdgcn_mfma_f32_16x16x32_bf16(af, bfr, acc[n], 0, 0, 0);
        }
    }
    #pragma unroll
    for (int n = 0; n < 8; ++n) {
        int f = n * 16 + l15;
        #pragma unroll
        for (int r = 0; r < 4; ++r) {
            int row = row0 + l4 * 4 + r;
            int t = row >> 8;
            int b = row & 255;
            out[(size_t)b * (TOUT * FEAT) + (size_t)t * FEAT + f] = acc[n][r];
        }
    }
}

// ---------------------------------------------------------------------------
extern "C" void kernel_launch(void* const* d_in, const int* in_sizes, int n_in,
                              void* d_out, int out_size, void* d_ws, size_t ws_size,
                              hipStream_t stream) {
    const float* x       = (const float*)d_in[0];
    const float* enc_Wih = (const float*)d_in[1];
    const float* enc_Whh = (const float*)d_in[2];
    const float* enc_b   = (const float*)d_in[3];
    const float* dec_Wih = (const float*)d_in[4];
    const float* dec_Whh = (const float*)d_in[5];
    const float* dec_b   = (const float*)d_in[6];
    const float* W_lin   = (const float*)d_in[7];
    float* out = (float*)d_out;

    char* p = (char*)d_ws;
    auto alloc = [&](size_t bytes) -> void* {
        void* r = (void*)p;
        p += (bytes + 255) & ~(size_t)255;
        return r;
    };
    bf16_t* Xbf    = (bf16_t*)alloc((size_t)TIN * BATCH * FEAT * 2);   // 11 MB
    bf16_t* Wenc   = (bf16_t*)alloc((size_t)2048 * 640 * 2);           // 2.6 MB
    bf16_t* Wdec1  = (bf16_t*)alloc((size_t)2048 * 640 * 2);           // 2.6 MB
    bf16_t* Wcomb  = (bf16_t*)alloc((size_t)2048 * HID * 2);           // 2.1 MB
    bf16_t* Wlinb  = (bf16_t*)alloc((size_t)FEAT * HID * 2);           // 128 KB
    bf16_t* hbufA  = (bf16_t*)alloc((size_t)BATCH * HID * 2);          // 256 KB
    bf16_t* hbufB  = (bf16_t*)alloc((size_t)BATCH * HID * 2);          // 256 KB
    bf16_t* Hdec   = (bf16_t*)alloc((size_t)TOUT * BATCH * HID * 2);   // 12.6 MB
    unsigned int* flags  = (unsigned int*)alloc((size_t)NGRP * NJT * 4);
    unsigned int* xccbuf = (unsigned int*)alloc((size_t)NGRP * NJT * 4);

    // per-launch state init (replay-safe)
    (void)hipMemsetAsync(hbufA, 0, (size_t)BATCH * HID * 2, stream);
    (void)hipMemsetAsync(flags, 0, (size_t)NGRP * NJT * 4, stream);
    (void)hipMemsetAsync(xccbuf, 0, (size_t)NGRP * NJT * 4, stream);

    // precompute
    cast_x_kernel<<<(BATCH * TIN * (FEAT / 4) + 255) / 256, 256, 0, stream>>>(x, Xbf);
    cast_wcat_kernel<<<(2048 * 160 + 255) / 256, 256, 0, stream>>>(enc_Wih, enc_Whh, Wenc);
    cast_wcat_kernel<<<(2048 * 160 + 255) / 256, 256, 0, stream>>>(dec_Wih, dec_Whh, Wdec1);
    cast_wlin_kernel<<<(FEAT * HID / 4 + 255) / 256, 256, 0, stream>>>(W_lin, Wlinb);
    build_wcomb_kernel<<<dim3(2048 / 64, HID / 64), 256, 0, stream>>>(dec_Wih, dec_Whh, W_lin, Wcomb);

    // all 216 recurrent steps in one persistent kernel
    lstm_persist<<<NGRP * NJT, 256, 0, stream>>>(Xbf, Wenc, enc_b, Wdec1, Wcomb, dec_b,
                                                 hbufA, hbufB, Hdec, flags, xccbuf);

    // batched output projection (48 x 256 rows @ W_lin^T)
    final_proj_kernel<<<(TOUT * BATCH) / 32, 128, 0, stream>>>(Hdec, Wlinb, out);
}